// Round 2
// baseline (1073.561 us; speedup 1.0000x reference)
//
#include <hip/hip_runtime.h>
#include <hip/hip_bf16.h>

// ---------------- problem constants ----------------
#define BG     128        // graphs
#define NPG    512        // nodes per graph
#define NNODE  65536      // BG*NPG
#define EDGES  1048576    // BG*8192
#define NHID   128
#define DCAT   384
#define KKEEP  128        // kept nodes per (graph,cluster)
#define NPOOL  32768      // 2*BG*KKEEP
#define NGG    256        // pooled groups (2*BG)

// ---------------- workspace layout (bytes) ----------------
#define OFF_HCAT   0ull                       // 65536*384 f32 = 100663296
#define OFF_XW     100663296ull               // 65536*128 f32 = 33554432 (reused: xwp, hp)
#define OFF_DINV   134217728ull               // 65536 f32
#define OFF_DINVP  134479872ull               // 32768 f32
#define OFF_OFFA   134610944ull               // 65537 int (row offsets, shared full/pooled)
#define OFF_CNT    134873344ull               // 65536 int
#define OFF_ESRC   135135488ull               // 1048576 int (edge src lists, shared)
#define OFF_XR     139329792ull               // 65536 f32
#define OFF_XS     139591936ull               // 65536 f32
#define OFF_SCORE  139854080ull               // 65536 f32
#define OFF_POS    140116224ull               // 65536 int
#define OFF_KEEPN  140378368ull               // 32768 int
#define OFF_KEEPS  140509440ull               // 32768 f32
#define OFF_SUMS   140640512ull               // 256 int scan partials
#define OFF_XSUM   140644608ull               // 256*128 f32
#define OFF_CG     140775680ull               // 256*128 f32
#define OFF_ALPHA  140906752ull               // 32768 f32
#define OFF_PVEC   141037824ull               // 256*128 f32

// ---------------- CSR build ----------------
__global__ void k_hist(const int* __restrict__ dst, int* __restrict__ cnt, int nE) {
    int e = blockIdx.x * blockDim.x + threadIdx.x;
    if (e < nE) atomicAdd(&cnt[dst[e]], 1);
}

__global__ void k_hist_p(const int* __restrict__ src, const int* __restrict__ dst,
                         const int* __restrict__ pos, int* __restrict__ cnt, int nE) {
    int e = blockIdx.x * blockDim.x + threadIdx.x;
    if (e >= nE) return;
    int s = src[e], d = dst[e];
    if ((((s ^ d) >> 8) & 1) != 0) return;    // must be same cluster side
    int ps = pos[s], pd = pos[d];
    if (ps >= 0 && pd >= 0) atomicAdd(&cnt[pd], 1);
}

__global__ void k_scan_a(const int* __restrict__ cnt, int* __restrict__ off,
                         int* __restrict__ sums, int n) {
    __shared__ int sh[256];
    int t = threadIdx.x;
    int i = blockIdx.x * 256 + t;
    int v = (i < n) ? cnt[i] : 0;
    sh[t] = v;
    __syncthreads();
    for (int d = 1; d < 256; d <<= 1) {
        int a = (t >= d) ? sh[t - d] : 0;
        __syncthreads();
        sh[t] += a;
        __syncthreads();
    }
    if (i < n) off[i] = sh[t] - v;            // local exclusive
    if (t == 255) sums[blockIdx.x] = sh[255]; // block total
}

__global__ void k_scan_b(int* __restrict__ sums, int nb, int* __restrict__ off, int n) {
    __shared__ int sh[256];
    int t = threadIdx.x;
    int v = (t < nb) ? sums[t] : 0;
    sh[t] = v;
    __syncthreads();
    for (int d = 1; d < 256; d <<= 1) {
        int a = (t >= d) ? sh[t - d] : 0;
        __syncthreads();
        sh[t] += a;
        __syncthreads();
    }
    if (t < nb) sums[t] = sh[t] - v;          // exclusive block offsets
    if (t == 255) off[n] = sh[255];           // grand total
}

__global__ void k_scan_c(int* __restrict__ off, const int* __restrict__ sums, int n) {
    int i = blockIdx.x * blockDim.x + threadIdx.x;
    if (i < n) off[i] += sums[i >> 8];
}

__global__ void k_fill(const int* __restrict__ src, const int* __restrict__ dst,
                       const int* __restrict__ off, int* __restrict__ cur,
                       int* __restrict__ esrc, int nE) {
    int e = blockIdx.x * blockDim.x + threadIdx.x;
    if (e >= nE) return;
    int d = dst[e];
    int p = off[d] + atomicAdd(&cur[d], 1);
    esrc[p] = src[e];
}

__global__ void k_fill_p(const int* __restrict__ src, const int* __restrict__ dst,
                         const int* __restrict__ pos, const int* __restrict__ off,
                         int* __restrict__ cur, int* __restrict__ esrc, int nE) {
    int e = blockIdx.x * blockDim.x + threadIdx.x;
    if (e >= nE) return;
    int s = src[e], d = dst[e];
    if ((((s ^ d) >> 8) & 1) != 0) return;
    int ps = pos[s], pd = pos[d];
    if (ps < 0 || pd < 0) return;
    int p = off[pd] + atomicAdd(&cur[pd], 1);
    esrc[p] = ps;
}

// deterministic per-segment order (atomic fill order is nondeterministic)
__global__ void k_segsort(const int* __restrict__ off, int* __restrict__ esrc, int n) {
    int v = blockIdx.x * blockDim.x + threadIdx.x;
    if (v >= n) return;
    int a = off[v], b = off[v + 1];
    for (int i = a + 1; i < b; ++i) {
        int key = esrc[i];
        int j = i - 1;
        while (j >= a && esrc[j] > key) { esrc[j + 1] = esrc[j]; --j; }
        esrc[j + 1] = key;
    }
}

__global__ void k_dinv(const int* __restrict__ off, float* __restrict__ dinv, int n) {
    int v = blockIdx.x * blockDim.x + threadIdx.x;
    if (v >= n) return;
    float deg = 1.0f + (float)(off[v + 1] - off[v]);
    dinv[v] = 1.0f / sqrtf(deg);
}

// ---------------- tiled f32 matmul: C[M,N] = A[M,K] @ B[K,N] ----------------
// BM=64 BN=64 BK=32, 256 threads, 4x4 per thread. GATHER: A row = hcat[rowmap[m]]*scale[m]
template <bool GATHER>
__global__ void __launch_bounds__(256)
k_matmul(const float* __restrict__ A, int lda,
         const int* __restrict__ rowmap, const float* __restrict__ rowscale,
         const float* __restrict__ B, int ldb, int Kdim,
         float* __restrict__ C, int ldc) {
    __shared__ float As[32][68];
    __shared__ float Bs[32][68];
    int t  = threadIdx.x;
    int m0 = blockIdx.y * 64;
    int n0 = blockIdx.x * 64;
    int tm = t >> 4, tn = t & 15;
    int ar = t >> 3;             // 0..31
    int ak = (t & 7) << 2;       // 0..28
    int br = t >> 4;             // 0..15
    int bn = (t & 15) << 2;      // 0..60
    float acc[4][4] = {};
    for (int k0 = 0; k0 < Kdim; k0 += 32) {
#pragma unroll
        for (int p = 0; p < 2; ++p) {
            int m = ar + p * 32;
            float4 a4;
            if (GATHER) {
                int row = rowmap[m0 + m];
                float sc = rowscale[m0 + m];
                a4 = *reinterpret_cast<const float4*>(&A[(size_t)row * lda + k0 + ak]);
                a4.x *= sc; a4.y *= sc; a4.z *= sc; a4.w *= sc;
            } else {
                a4 = *reinterpret_cast<const float4*>(&A[(size_t)(m0 + m) * lda + k0 + ak]);
            }
            As[ak + 0][m] = a4.x; As[ak + 1][m] = a4.y;
            As[ak + 2][m] = a4.z; As[ak + 3][m] = a4.w;
        }
#pragma unroll
        for (int p = 0; p < 2; ++p) {
            int kk = br + p * 16;
            float4 b4 = *reinterpret_cast<const float4*>(&B[(size_t)(k0 + kk) * ldb + n0 + bn]);
            *reinterpret_cast<float4*>(&Bs[kk][bn]) = b4;
        }
        __syncthreads();
#pragma unroll
        for (int kk = 0; kk < 32; ++kk) {
            float4 av = *reinterpret_cast<const float4*>(&As[kk][tm << 2]);
            float4 bv = *reinterpret_cast<const float4*>(&Bs[kk][tn << 2]);
            float aa[4] = {av.x, av.y, av.z, av.w};
            float bb[4] = {bv.x, bv.y, bv.z, bv.w};
#pragma unroll
            for (int i = 0; i < 4; ++i)
#pragma unroll
                for (int j = 0; j < 4; ++j)
                    acc[i][j] = fmaf(aa[i], bb[j], acc[i][j]);
        }
        __syncthreads();
    }
#pragma unroll
    for (int i = 0; i < 4; ++i) {
        int m = m0 + (tm << 2) + i;
#pragma unroll
        for (int j = 0; j < 4; ++j)
            C[(size_t)m * ldc + n0 + (tn << 2) + j] = acc[i][j];
    }
}

// ---------------- GCN aggregate: out = relu(sum_in dinv[s]*dinv[v]*xw[s] + dinv^2*xw[v] + b)
__global__ void k_aggregate(const float* __restrict__ xw, const int* __restrict__ off,
                            const int* __restrict__ esrc, const float* __restrict__ dinv,
                            const float* __restrict__ bias, float* __restrict__ out,
                            int ldout, int n) {
    int c = threadIdx.x & 127;
    int v = (blockIdx.x << 1) + (threadIdx.x >> 7);
    if (v >= n) return;
    float dv = dinv[v];
    float acc = 0.f;
    int e0 = off[v], e1 = off[v + 1];
    for (int j = e0; j < e1; ++j) {
        int s = esrc[j];
        acc = fmaf(dinv[s] * dv, xw[(size_t)s * 128 + c], acc);
    }
    acc += dv * dv * xw[(size_t)v * 128 + c];
    acc += bias[c];
    out[(size_t)v * ldout + c] = fmaxf(acc, 0.f);
}

// ---------------- scoring ----------------
__global__ void k_xrxs(const float* __restrict__ hcat, const float* __restrict__ Wr,
                       const float* __restrict__ Ws, float* __restrict__ xr,
                       float* __restrict__ xs) {
    int wid  = (blockIdx.x * 256 + threadIdx.x) >> 6;   // node (wave per node)
    int lane = threadIdx.x & 63;
    if (wid >= NNODE) return;
    float ar = 0.f, as = 0.f;
    for (int k = lane; k < DCAT; k += 64) {
        float h = hcat[(size_t)wid * DCAT + k];
        ar = fmaf(h, Wr[k], ar);
        as = fmaf(h, Ws[k], as);
    }
    for (int o = 32; o; o >>= 1) { ar += __shfl_down(ar, o); as += __shfl_down(as, o); }
    if (lane == 0) { xr[wid] = ar; xs[wid] = as; }
}

__global__ void k_score(const int* __restrict__ off, const int* __restrict__ esrc,
                        const float* __restrict__ xr, const float* __restrict__ xs,
                        const float* __restrict__ pb, float* __restrict__ score) {
    int v = blockIdx.x * blockDim.x + threadIdx.x;
    if (v >= NNODE) return;
    int side = (v >> 8) & 1;
    float acc = 0.f;
    int e0 = off[v], e1 = off[v + 1];
    for (int j = e0; j < e1; ++j) {
        int s = esrc[j];
        if (((s >> 8) & 1) == side) acc += xr[s];
    }
    score[v] = tanhf(acc + xs[v] + pb[0]);
}

// ---------------- per-(graph,cluster) top-K via bitonic sort ----------------
__global__ void k_topk(const float* __restrict__ score, int* __restrict__ keepn,
                       float* __restrict__ keeps, int* __restrict__ pos) {
    __shared__ unsigned long long keys[256];
    __shared__ float sc[256];
    __shared__ int rankof[256];
    int g = blockIdx.x & 127, cl = blockIdx.x >> 7;
    int t = threadIdx.x;
    int node = g * NPG + cl * 256 + t;
    float s = score[node];
    sc[t] = s;
    rankof[t] = -1;
    unsigned u = __float_as_uint(s);
    u = (u & 0x80000000u) ? ~u : (u | 0x80000000u); // ascending order map
    unsigned dk = ~u;                               // descending
    keys[t] = ((unsigned long long)dk << 32) | (unsigned)t;
    __syncthreads();
    for (int k = 2; k <= 256; k <<= 1)
        for (int j = k >> 1; j > 0; j >>= 1) {
            int ixj = t ^ j;
            if (ixj > t) {
                bool up = ((t & k) == 0);
                unsigned long long A = keys[t], Bk = keys[ixj];
                if ((A > Bk) == up) { keys[t] = Bk; keys[ixj] = A; }
            }
            __syncthreads();
        }
    if (t < KKEEP) {
        int idx = (int)(keys[t] & 0xffffffffu);
        int pool = cl * (BG * KKEEP) + g * KKEEP + t;
        keepn[pool] = g * NPG + cl * 256 + idx;
        keeps[pool] = sc[idx];
        rankof[idx] = t;
    }
    __syncthreads();
    int r = rankof[t];
    pos[node] = (r >= 0) ? (cl * (BG * KKEEP) + g * KKEEP + r) : -1;
}

// ---------------- attention pooling ----------------
__global__ void k_xsum(const float* __restrict__ hp, float* __restrict__ xsum) {
    int gg = blockIdx.x, t = threadIdx.x; // 256 blocks x 128 threads
    float a = 0.f;
    for (int i = 0; i < KKEEP; ++i) a += hp[(size_t)(gg * KKEEP + i) * 128 + t];
    xsum[gg * 128 + t] = a * (1.0f / (float)KKEEP);
}

__global__ void k_cg(const float* __restrict__ xsum, const float* __restrict__ gpW,
                     float* __restrict__ cg) {
    __shared__ float xl[128];
    int gg = blockIdx.x, t = threadIdx.x;
    xl[t] = xsum[gg * 128 + t];
    __syncthreads();
    float a = 0.f;
    for (int k = 0; k < 128; ++k) a = fmaf(xl[k], gpW[k * 128 + t], a);
    cg[gg * 128 + t] = tanhf(a);
}

__global__ void k_alpha(const float* __restrict__ hp, const float* __restrict__ cg,
                        float* __restrict__ alpha) {
    int node = (blockIdx.x * 256 + threadIdx.x) >> 6;
    int lane = threadIdx.x & 63;
    if (node >= NPOOL) return;
    int gg = node >> 7;
    float a = 0.f;
    for (int k = lane; k < 128; k += 64)
        a = fmaf(hp[(size_t)node * 128 + k], cg[gg * 128 + k], a);
    for (int o = 32; o; o >>= 1) a += __shfl_down(a, o);
    if (lane == 0) alpha[node] = 1.f / (1.f + expf(-a));
}

__global__ void k_wsum(const float* __restrict__ hp, const float* __restrict__ alpha,
                       float* __restrict__ pvec) {
    int gg = blockIdx.x, t = threadIdx.x;
    float a = 0.f;
    for (int i = 0; i < KKEEP; ++i) {
        int node = gg * KKEEP + i;
        a = fmaf(alpha[node], hp[(size_t)node * 128 + t], a);
    }
    pvec[gg * 128 + t] = a;
}

// ---------------- MLP head + outputs (f32 out) ----------------
__global__ void k_head(const float* __restrict__ pvec,
                       const float* __restrict__ l1W, const float* __restrict__ l1b,
                       const float* __restrict__ l2W, const float* __restrict__ l2b,
                       const float* __restrict__ l3W, const float* __restrict__ l3b,
                       float* __restrict__ out) {
    __shared__ float pv[256], h1[128], h2[64];
    int g = blockIdx.x, t = threadIdx.x;
    pv[t]       = pvec[g * 128 + t];
    pv[128 + t] = pvec[(128 + g) * 128 + t];
    __syncthreads();
    float a = l1b[t];
    for (int k = 0; k < 256; ++k) a = fmaf(pv[k], l1W[k * 128 + t], a);
    h1[t] = fmaxf(a, 0.f);
    __syncthreads();
    if (t < 64) {
        float a2 = l2b[t];
        for (int k = 0; k < 128; ++k) a2 = fmaf(h1[k], l2W[k * 64 + t], a2);
        h2[t] = fmaxf(a2, 0.f);
    }
    __syncthreads();
    if (t < 10) {
        float a3 = l3b[t];
        for (int k = 0; k < 64; ++k) a3 = fmaf(h2[k], l3W[k * 10 + t], a3);
        out[65536 + g * 10 + t] = a3;
    }
}

__global__ void k_batchout(float* __restrict__ out) {
    int i = blockIdx.x * blockDim.x + threadIdx.x;
    if (i >= 65536) return;
    int v = (i < 32768) ? (i >> 8) : ((i - 32768) >> 8) + 128;
    out[i] = (float)v;
}

// ---------------- launch ----------------
extern "C" void kernel_launch(void* const* d_in, const int* in_sizes, int n_in,
                              void* d_out, int out_size, void* d_ws, size_t ws_size,
                              hipStream_t stream) {
    const float* x    = (const float*)d_in[0];
    const int*   ei   = (const int*)d_in[1];
    const int*   esrc_in = ei;
    const int*   edst_in = ei + EDGES;
    const float* W1 = (const float*)d_in[2];  const float* b1 = (const float*)d_in[3];
    const float* W2 = (const float*)d_in[4];  const float* b2 = (const float*)d_in[5];
    const float* W3 = (const float*)d_in[6];  const float* b3 = (const float*)d_in[7];
    const float* pWr = (const float*)d_in[8]; const float* pWs = (const float*)d_in[9];
    const float* pb  = (const float*)d_in[10];
    const float* fW  = (const float*)d_in[11]; const float* fb = (const float*)d_in[12];
    const float* gpW = (const float*)d_in[13];
    const float* l1W = (const float*)d_in[14]; const float* l1b = (const float*)d_in[15];
    const float* l2W = (const float*)d_in[16]; const float* l2b = (const float*)d_in[17];
    const float* l3W = (const float*)d_in[18]; const float* l3b = (const float*)d_in[19];
    float* out = (float*)d_out;

    char* ws = (char*)d_ws;
    float* hcat  = (float*)(ws + OFF_HCAT);
    float* xw    = (float*)(ws + OFF_XW);
    float* xwp   = (float*)(ws + OFF_XW);                 // reuse after conv3
    float* hp    = (float*)(ws + OFF_XW + 16777216ull);
    float* dinv  = (float*)(ws + OFF_DINV);
    float* dinvp = (float*)(ws + OFF_DINVP);
    int*   offA  = (int*)(ws + OFF_OFFA);
    int*   cnt   = (int*)(ws + OFF_CNT);
    int*   esrc  = (int*)(ws + OFF_ESRC);
    float* xr    = (float*)(ws + OFF_XR);
    float* xs    = (float*)(ws + OFF_XS);
    float* score = (float*)(ws + OFF_SCORE);
    int*   pos   = (int*)(ws + OFF_POS);
    int*   keepn = (int*)(ws + OFF_KEEPN);
    float* keeps = (float*)(ws + OFF_KEEPS);
    int*   sums  = (int*)(ws + OFF_SUMS);
    float* xsum  = (float*)(ws + OFF_XSUM);
    float* cg    = (float*)(ws + OFF_CG);
    float* alpha = (float*)(ws + OFF_ALPHA);
    float* pvec  = (float*)(ws + OFF_PVEC);

    // ---- full-graph CSR (by dst) ----
    hipMemsetAsync(cnt, 0, NNODE * sizeof(int), stream);
    k_hist<<<EDGES / 256, 256, 0, stream>>>(edst_in, cnt, EDGES);
    k_scan_a<<<NNODE / 256, 256, 0, stream>>>(cnt, offA, sums, NNODE);
    k_scan_b<<<1, 256, 0, stream>>>(sums, NNODE / 256, offA, NNODE);
    k_scan_c<<<NNODE / 256, 256, 0, stream>>>(offA, sums, NNODE);
    hipMemsetAsync(cnt, 0, NNODE * sizeof(int), stream);
    k_fill<<<EDGES / 256, 256, 0, stream>>>(esrc_in, edst_in, offA, cnt, esrc, EDGES);
    k_segsort<<<NNODE / 256, 256, 0, stream>>>(offA, esrc, NNODE);
    k_dinv<<<NNODE / 256, 256, 0, stream>>>(offA, dinv, NNODE);

    // ---- 3 GCN layers into hcat column slices ----
    dim3 mmg(2, NNODE / 64);
    k_matmul<false><<<mmg, 256, 0, stream>>>(x, 128, nullptr, nullptr, W1, 128, 128, xw, 128);
    k_aggregate<<<NNODE / 2, 256, 0, stream>>>(xw, offA, esrc, dinv, b1, hcat + 0, DCAT, NNODE);
    k_matmul<false><<<mmg, 256, 0, stream>>>(hcat, DCAT, nullptr, nullptr, W2, 128, 128, xw, 128);
    k_aggregate<<<NNODE / 2, 256, 0, stream>>>(xw, offA, esrc, dinv, b2, hcat + 128, DCAT, NNODE);
    k_matmul<false><<<mmg, 256, 0, stream>>>(hcat + 128, DCAT, nullptr, nullptr, W3, 128, 128, xw, 128);
    k_aggregate<<<NNODE / 2, 256, 0, stream>>>(xw, offA, esrc, dinv, b3, hcat + 256, DCAT, NNODE);

    // ---- SAGPool scoring + top-K ----
    k_xrxs<<<NNODE / 4, 256, 0, stream>>>(hcat, pWr, pWs, xr, xs);
    k_score<<<NNODE / 256, 256, 0, stream>>>(offA, esrc, xr, xs, pb, score);
    k_topk<<<256, 256, 0, stream>>>(score, keepn, keeps, pos);

    // ---- pooled CSR (filtered, remapped edges) ----
    hipMemsetAsync(cnt, 0, NPOOL * sizeof(int), stream);
    k_hist_p<<<EDGES / 256, 256, 0, stream>>>(esrc_in, edst_in, pos, cnt, EDGES);
    k_scan_a<<<NPOOL / 256, 256, 0, stream>>>(cnt, offA, sums, NPOOL);
    k_scan_b<<<1, 256, 0, stream>>>(sums, NPOOL / 256, offA, NPOOL);
    k_scan_c<<<NPOOL / 256, 256, 0, stream>>>(offA, sums, NPOOL);
    hipMemsetAsync(cnt, 0, NPOOL * sizeof(int), stream);
    k_fill_p<<<EDGES / 256, 256, 0, stream>>>(esrc_in, edst_in, pos, offA, cnt, esrc, EDGES);
    k_segsort<<<NPOOL / 256, 256, 0, stream>>>(offA, esrc, NPOOL);
    k_dinv<<<NPOOL / 256, 256, 0, stream>>>(offA, dinvp, NPOOL);

    // ---- pooled GCN conv (gather+scale A rows from hcat) ----
    dim3 mmp(2, NPOOL / 64);
    k_matmul<true><<<mmp, 256, 0, stream>>>(hcat, DCAT, keepn, keeps, fW, 128, DCAT, xwp, 128);
    k_aggregate<<<NPOOL / 2, 256, 0, stream>>>(xwp, offA, esrc, dinvp, fb, hp, 128, NPOOL);

    // ---- attention pool + head ----
    k_xsum<<<NGG, 128, 0, stream>>>(hp, xsum);
    k_cg<<<NGG, 128, 0, stream>>>(xsum, gpW, cg);
    k_alpha<<<NPOOL / 4, 256, 0, stream>>>(hp, cg, alpha);
    k_wsum<<<NGG, 128, 0, stream>>>(hp, alpha, pvec);
    k_head<<<BG, 128, 0, stream>>>(pvec, l1W, l1b, l2W, l2b, l3W, l3b, out);
    k_batchout<<<256, 256, 0, stream>>>(out);
}

// Round 3
// 753.382 us; speedup vs baseline: 1.4250x; 1.4250x over previous
//
#include <hip/hip_runtime.h>
#include <hip/hip_bf16.h>

// ---------------- problem constants ----------------
#define BG     128        // graphs
#define NPG    512        // nodes per graph
#define NNODE  65536      // BG*NPG
#define EDGES  1048576    // BG*8192
#define NHID   128
#define DCAT   384
#define KKEEP  128        // kept nodes per (graph,cluster)
#define NPOOL  32768      // 2*BG*KKEEP
#define NGG    256        // pooled groups (2*BG)

// ---------------- workspace layout (bytes) ----------------
#define OFF_HCAT   0ull                       // 65536*384 f32 = 100663296
#define OFF_XW     100663296ull               // 65536*128 f32 = 33554432 (reused: xwp, hp)
#define OFF_DINV   134217728ull               // 65536 f32
#define OFF_DINVP  134479872ull               // 32768 f32
#define OFF_OFFA   134610944ull               // 65537 int (row offsets, shared full/pooled)
#define OFF_CNT    134873344ull               // 65536 int
#define OFF_ESRC   135135488ull               // 1048576 int (edge src lists, shared)
#define OFF_XR     139329792ull               // 65536 f32
#define OFF_XS     139591936ull               // 65536 f32
#define OFF_SCORE  139854080ull               // 65536 f32
#define OFF_POS    140116224ull               // 65536 int
#define OFF_KEEPN  140378368ull               // 32768 int
#define OFF_KEEPS  140509440ull               // 32768 f32
#define OFF_SUMS   140640512ull               // 256 int scan partials
#define OFF_XSUM   140644608ull               // 256*128 f32
#define OFF_CG     140775680ull               // 256*128 f32
#define OFF_ALPHA  140906752ull               // 32768 f32
#define OFF_PVEC   141037824ull               // 256*128 f32

// ---------------- CSR build ----------------
__global__ void k_hist(const int* __restrict__ dst, int* __restrict__ cnt, int nE) {
    int e = blockIdx.x * blockDim.x + threadIdx.x;
    if (e < nE) atomicAdd(&cnt[dst[e]], 1);
}

__global__ void k_hist_p(const int* __restrict__ src, const int* __restrict__ dst,
                         const int* __restrict__ pos, int* __restrict__ cnt, int nE) {
    int e = blockIdx.x * blockDim.x + threadIdx.x;
    if (e >= nE) return;
    int s = src[e], d = dst[e];
    if ((((s ^ d) >> 8) & 1) != 0) return;    // must be same cluster side
    int ps = pos[s], pd = pos[d];
    if (ps >= 0 && pd >= 0) atomicAdd(&cnt[pd], 1);
}

__global__ void k_scan_a(const int* __restrict__ cnt, int* __restrict__ off,
                         int* __restrict__ sums, int n) {
    __shared__ int sh[256];
    int t = threadIdx.x;
    int i = blockIdx.x * 256 + t;
    int v = (i < n) ? cnt[i] : 0;
    sh[t] = v;
    __syncthreads();
    for (int d = 1; d < 256; d <<= 1) {
        int a = (t >= d) ? sh[t - d] : 0;
        __syncthreads();
        sh[t] += a;
        __syncthreads();
    }
    if (i < n) off[i] = sh[t] - v;            // local exclusive
    if (t == 255) sums[blockIdx.x] = sh[255]; // block total
}

__global__ void k_scan_b(int* __restrict__ sums, int nb, int* __restrict__ off, int n) {
    __shared__ int sh[256];
    int t = threadIdx.x;
    int v = (t < nb) ? sums[t] : 0;
    sh[t] = v;
    __syncthreads();
    for (int d = 1; d < 256; d <<= 1) {
        int a = (t >= d) ? sh[t - d] : 0;
        __syncthreads();
        sh[t] += a;
        __syncthreads();
    }
    if (t < nb) sums[t] = sh[t] - v;          // exclusive block offsets
    if (t == 255) off[n] = sh[255];           // grand total
}

__global__ void k_scan_c(int* __restrict__ off, const int* __restrict__ sums, int n) {
    int i = blockIdx.x * blockDim.x + threadIdx.x;
    if (i < n) off[i] += sums[i >> 8];
}

__global__ void k_fill(const int* __restrict__ src, const int* __restrict__ dst,
                       const int* __restrict__ off, int* __restrict__ cur,
                       int* __restrict__ esrc, int nE) {
    int e = blockIdx.x * blockDim.x + threadIdx.x;
    if (e >= nE) return;
    int d = dst[e];
    int p = off[d] + atomicAdd(&cur[d], 1);
    esrc[p] = src[e];
}

__global__ void k_fill_p(const int* __restrict__ src, const int* __restrict__ dst,
                         const int* __restrict__ pos, const int* __restrict__ off,
                         int* __restrict__ cur, int* __restrict__ esrc, int nE) {
    int e = blockIdx.x * blockDim.x + threadIdx.x;
    if (e >= nE) return;
    int s = src[e], d = dst[e];
    if ((((s ^ d) >> 8) & 1) != 0) return;
    int ps = pos[s], pd = pos[d];
    if (ps < 0 || pd < 0) return;
    int p = off[pd] + atomicAdd(&cur[pd], 1);
    esrc[p] = ps;
}

// deterministic per-segment order (atomic fill order is nondeterministic)
__global__ void k_segsort(const int* __restrict__ off, int* __restrict__ esrc, int n) {
    int v = blockIdx.x * blockDim.x + threadIdx.x;
    if (v >= n) return;
    int a = off[v], b = off[v + 1];
    for (int i = a + 1; i < b; ++i) {
        int key = esrc[i];
        int j = i - 1;
        while (j >= a && esrc[j] > key) { esrc[j + 1] = esrc[j]; --j; }
        esrc[j + 1] = key;
    }
}

__global__ void k_dinv(const int* __restrict__ off, float* __restrict__ dinv, int n) {
    int v = blockIdx.x * blockDim.x + threadIdx.x;
    if (v >= n) return;
    float deg = 1.0f + (float)(off[v + 1] - off[v]);
    dinv[v] = 1.0f / sqrtf(deg);
}

// ---------------- tiled f32 matmul: C[M,N] = A[M,K] @ B[K,N] ----------------
// BM=64 BN=64 BK=32, 256 threads, 4x4 per thread. GATHER: A row = hcat[rowmap[m]]*scale[m]
template <bool GATHER>
__global__ void __launch_bounds__(256)
k_matmul(const float* __restrict__ A, int lda,
         const int* __restrict__ rowmap, const float* __restrict__ rowscale,
         const float* __restrict__ B, int ldb, int Kdim,
         float* __restrict__ C, int ldc) {
    __shared__ float As[32][68];
    __shared__ float Bs[32][68];
    int t  = threadIdx.x;
    int m0 = blockIdx.y * 64;
    int n0 = blockIdx.x * 64;
    int tm = t >> 4, tn = t & 15;
    int ar = t >> 3;             // 0..31
    int ak = (t & 7) << 2;       // 0..28
    int br = t >> 4;             // 0..15
    int bn = (t & 15) << 2;      // 0..60
    float acc[4][4] = {};
    for (int k0 = 0; k0 < Kdim; k0 += 32) {
#pragma unroll
        for (int p = 0; p < 2; ++p) {
            int m = ar + p * 32;
            float4 a4;
            if (GATHER) {
                int row = rowmap[m0 + m];
                float sc = rowscale[m0 + m];
                a4 = *reinterpret_cast<const float4*>(&A[(size_t)row * lda + k0 + ak]);
                a4.x *= sc; a4.y *= sc; a4.z *= sc; a4.w *= sc;
            } else {
                a4 = *reinterpret_cast<const float4*>(&A[(size_t)(m0 + m) * lda + k0 + ak]);
            }
            As[ak + 0][m] = a4.x; As[ak + 1][m] = a4.y;
            As[ak + 2][m] = a4.z; As[ak + 3][m] = a4.w;
        }
#pragma unroll
        for (int p = 0; p < 2; ++p) {
            int kk = br + p * 16;
            float4 b4 = *reinterpret_cast<const float4*>(&B[(size_t)(k0 + kk) * ldb + n0 + bn]);
            *reinterpret_cast<float4*>(&Bs[kk][bn]) = b4;
        }
        __syncthreads();
#pragma unroll
        for (int kk = 0; kk < 32; ++kk) {
            float4 av = *reinterpret_cast<const float4*>(&As[kk][tm << 2]);
            float4 bv = *reinterpret_cast<const float4*>(&Bs[kk][tn << 2]);
            float aa[4] = {av.x, av.y, av.z, av.w};
            float bb[4] = {bv.x, bv.y, bv.z, bv.w};
#pragma unroll
            for (int i = 0; i < 4; ++i)
#pragma unroll
                for (int j = 0; j < 4; ++j)
                    acc[i][j] = fmaf(aa[i], bb[j], acc[i][j]);
        }
        __syncthreads();
    }
#pragma unroll
    for (int i = 0; i < 4; ++i) {
        int m = m0 + (tm << 2) + i;
#pragma unroll
        for (int j = 0; j < 4; ++j)
            C[(size_t)m * ldc + n0 + (tn << 2) + j] = acc[i][j];
    }
}

// ---------------- GCN aggregate via per-graph LDS staging ----------------
// One block per (group, channel-block). Stage group's xw rows scaled by dinv[s]
// into LDS, then each wave sums rows for one dst node (wave-uniform edge loop).
// out[v][ch] = relu(dinv[v] * (sum_edges staged[s] + staged[v]) + bias)
template <int NODESG, int CHB>
__global__ void __launch_bounds__(512)
k_agg_lds(const float* __restrict__ xw, const int* __restrict__ off,
          const int* __restrict__ esrc, const float* __restrict__ dinv,
          const float* __restrict__ bias, float* __restrict__ out, int ldout) {
    __shared__ float sx[NODESG * CHB];
    __shared__ float sdv[NODESG];
    const int NHALF = 128 / CHB;            // channel-blocks per row
    const int NSLOT = 512 / CHB;            // nodes processed in parallel
    int t    = threadIdx.x;
    int g    = blockIdx.x / NHALF;
    int half = blockIdx.x % NHALF;
    int ch0  = half * CHB;
    int gbase = g * NODESG;
    int ch   = t % CHB;
    int slot = t / CHB;

    for (int r = t; r < NODESG; r += 512) sdv[r] = dinv[gbase + r];
    __syncthreads();
    for (int r = slot; r < NODESG; r += NSLOT)
        sx[r * CHB + ch] = xw[(size_t)(gbase + r) * 128 + ch0 + ch] * sdv[r];
    __syncthreads();

    float bb = bias[ch0 + ch];
    int uslot = __builtin_amdgcn_readfirstlane(slot);
    for (int vi = uslot; vi < NODESG; vi += NSLOT) {
        int v = gbase + vi;
        int e0 = off[v], e1 = off[v + 1];
        float acc = sx[vi * CHB + ch];      // self-loop (carries dinv[v])
        int j = e0;
        for (; j + 3 < e1; j += 4) {
            float a0 = sx[(esrc[j + 0] & (NODESG - 1)) * CHB + ch];
            float a1 = sx[(esrc[j + 1] & (NODESG - 1)) * CHB + ch];
            float a2 = sx[(esrc[j + 2] & (NODESG - 1)) * CHB + ch];
            float a3 = sx[(esrc[j + 3] & (NODESG - 1)) * CHB + ch];
            acc += a0; acc += a1; acc += a2; acc += a3;
        }
        for (; j < e1; ++j)
            acc += sx[(esrc[j] & (NODESG - 1)) * CHB + ch];
        out[(size_t)v * ldout + ch0 + ch] = fmaxf(fmaf(sdv[vi], acc, bb), 0.f);
    }
}

// ---------------- scoring ----------------
__global__ void k_xrxs(const float* __restrict__ hcat, const float* __restrict__ Wr,
                       const float* __restrict__ Ws, float* __restrict__ xr,
                       float* __restrict__ xs) {
    int wid  = (blockIdx.x * 256 + threadIdx.x) >> 6;   // node (wave per node)
    int lane = threadIdx.x & 63;
    if (wid >= NNODE) return;
    float ar = 0.f, as = 0.f;
    for (int k = lane; k < DCAT; k += 64) {
        float h = hcat[(size_t)wid * DCAT + k];
        ar = fmaf(h, Wr[k], ar);
        as = fmaf(h, Ws[k], as);
    }
    for (int o = 32; o; o >>= 1) { ar += __shfl_down(ar, o); as += __shfl_down(as, o); }
    if (lane == 0) { xr[wid] = ar; xs[wid] = as; }
}

__global__ void k_score(const int* __restrict__ off, const int* __restrict__ esrc,
                        const float* __restrict__ xr, const float* __restrict__ xs,
                        const float* __restrict__ pb, float* __restrict__ score) {
    int v = blockIdx.x * blockDim.x + threadIdx.x;
    if (v >= NNODE) return;
    int side = (v >> 8) & 1;
    float acc = 0.f;
    int e0 = off[v], e1 = off[v + 1];
    for (int j = e0; j < e1; ++j) {
        int s = esrc[j];
        if (((s >> 8) & 1) == side) acc += xr[s];
    }
    score[v] = tanhf(acc + xs[v] + pb[0]);
}

// ---------------- per-(graph,cluster) top-K via bitonic sort ----------------
__global__ void k_topk(const float* __restrict__ score, int* __restrict__ keepn,
                       float* __restrict__ keeps, int* __restrict__ pos) {
    __shared__ unsigned long long keys[256];
    __shared__ float sc[256];
    __shared__ int rankof[256];
    int g = blockIdx.x & 127, cl = blockIdx.x >> 7;
    int t = threadIdx.x;
    int node = g * NPG + cl * 256 + t;
    float s = score[node];
    sc[t] = s;
    rankof[t] = -1;
    unsigned u = __float_as_uint(s);
    u = (u & 0x80000000u) ? ~u : (u | 0x80000000u); // ascending order map
    unsigned dk = ~u;                               // descending
    keys[t] = ((unsigned long long)dk << 32) | (unsigned)t;
    __syncthreads();
    for (int k = 2; k <= 256; k <<= 1)
        for (int j = k >> 1; j > 0; j >>= 1) {
            int ixj = t ^ j;
            if (ixj > t) {
                bool up = ((t & k) == 0);
                unsigned long long A = keys[t], Bk = keys[ixj];
                if ((A > Bk) == up) { keys[t] = Bk; keys[ixj] = A; }
            }
            __syncthreads();
        }
    if (t < KKEEP) {
        int idx = (int)(keys[t] & 0xffffffffu);
        int pool = cl * (BG * KKEEP) + g * KKEEP + t;
        keepn[pool] = g * NPG + cl * 256 + idx;
        keeps[pool] = sc[idx];
        rankof[idx] = t;
    }
    __syncthreads();
    int r = rankof[t];
    pos[node] = (r >= 0) ? (cl * (BG * KKEEP) + g * KKEEP + r) : -1;
}

// ---------------- attention pooling ----------------
__global__ void k_xsum(const float* __restrict__ hp, float* __restrict__ xsum) {
    int gg = blockIdx.x, t = threadIdx.x; // 256 blocks x 128 threads
    float a = 0.f;
    for (int i = 0; i < KKEEP; ++i) a += hp[(size_t)(gg * KKEEP + i) * 128 + t];
    xsum[gg * 128 + t] = a * (1.0f / (float)KKEEP);
}

__global__ void k_cg(const float* __restrict__ xsum, const float* __restrict__ gpW,
                     float* __restrict__ cg) {
    __shared__ float xl[128];
    int gg = blockIdx.x, t = threadIdx.x;
    xl[t] = xsum[gg * 128 + t];
    __syncthreads();
    float a = 0.f;
    for (int k = 0; k < 128; ++k) a = fmaf(xl[k], gpW[k * 128 + t], a);
    cg[gg * 128 + t] = tanhf(a);
}

__global__ void k_alpha(const float* __restrict__ hp, const float* __restrict__ cg,
                        float* __restrict__ alpha) {
    int node = (blockIdx.x * 256 + threadIdx.x) >> 6;
    int lane = threadIdx.x & 63;
    if (node >= NPOOL) return;
    int gg = node >> 7;
    float a = 0.f;
    for (int k = lane; k < 128; k += 64)
        a = fmaf(hp[(size_t)node * 128 + k], cg[gg * 128 + k], a);
    for (int o = 32; o; o >>= 1) a += __shfl_down(a, o);
    if (lane == 0) alpha[node] = 1.f / (1.f + expf(-a));
}

__global__ void k_wsum(const float* __restrict__ hp, const float* __restrict__ alpha,
                       float* __restrict__ pvec) {
    int gg = blockIdx.x, t = threadIdx.x;
    float a = 0.f;
    for (int i = 0; i < KKEEP; ++i) {
        int node = gg * KKEEP + i;
        a = fmaf(alpha[node], hp[(size_t)node * 128 + t], a);
    }
    pvec[gg * 128 + t] = a;
}

// ---------------- MLP head + outputs (f32 out) ----------------
__global__ void k_head(const float* __restrict__ pvec,
                       const float* __restrict__ l1W, const float* __restrict__ l1b,
                       const float* __restrict__ l2W, const float* __restrict__ l2b,
                       const float* __restrict__ l3W, const float* __restrict__ l3b,
                       float* __restrict__ out) {
    __shared__ float pv[256], h1[128], h2[64];
    int g = blockIdx.x, t = threadIdx.x;
    pv[t]       = pvec[g * 128 + t];
    pv[128 + t] = pvec[(128 + g) * 128 + t];
    __syncthreads();
    float a = l1b[t];
    for (int k = 0; k < 256; ++k) a = fmaf(pv[k], l1W[k * 128 + t], a);
    h1[t] = fmaxf(a, 0.f);
    __syncthreads();
    if (t < 64) {
        float a2 = l2b[t];
        for (int k = 0; k < 128; ++k) a2 = fmaf(h1[k], l2W[k * 64 + t], a2);
        h2[t] = fmaxf(a2, 0.f);
    }
    __syncthreads();
    if (t < 10) {
        float a3 = l3b[t];
        for (int k = 0; k < 64; ++k) a3 = fmaf(h2[k], l3W[k * 10 + t], a3);
        out[65536 + g * 10 + t] = a3;
    }
}

__global__ void k_batchout(float* __restrict__ out) {
    int i = blockIdx.x * blockDim.x + threadIdx.x;
    if (i >= 65536) return;
    int v = (i < 32768) ? (i >> 8) : ((i - 32768) >> 8) + 128;
    out[i] = (float)v;
}

// ---------------- launch ----------------
extern "C" void kernel_launch(void* const* d_in, const int* in_sizes, int n_in,
                              void* d_out, int out_size, void* d_ws, size_t ws_size,
                              hipStream_t stream) {
    const float* x    = (const float*)d_in[0];
    const int*   ei   = (const int*)d_in[1];
    const int*   esrc_in = ei;
    const int*   edst_in = ei + EDGES;
    const float* W1 = (const float*)d_in[2];  const float* b1 = (const float*)d_in[3];
    const float* W2 = (const float*)d_in[4];  const float* b2 = (const float*)d_in[5];
    const float* W3 = (const float*)d_in[6];  const float* b3 = (const float*)d_in[7];
    const float* pWr = (const float*)d_in[8]; const float* pWs = (const float*)d_in[9];
    const float* pb  = (const float*)d_in[10];
    const float* fW  = (const float*)d_in[11]; const float* fb = (const float*)d_in[12];
    const float* gpW = (const float*)d_in[13];
    const float* l1W = (const float*)d_in[14]; const float* l1b = (const float*)d_in[15];
    const float* l2W = (const float*)d_in[16]; const float* l2b = (const float*)d_in[17];
    const float* l3W = (const float*)d_in[18]; const float* l3b = (const float*)d_in[19];
    float* out = (float*)d_out;

    char* ws = (char*)d_ws;
    float* hcat  = (float*)(ws + OFF_HCAT);
    float* xw    = (float*)(ws + OFF_XW);
    float* xwp   = (float*)(ws + OFF_XW);                 // reuse after conv3
    float* hp    = (float*)(ws + OFF_XW + 16777216ull);
    float* dinv  = (float*)(ws + OFF_DINV);
    float* dinvp = (float*)(ws + OFF_DINVP);
    int*   offA  = (int*)(ws + OFF_OFFA);
    int*   cnt   = (int*)(ws + OFF_CNT);
    int*   esrc  = (int*)(ws + OFF_ESRC);
    float* xr    = (float*)(ws + OFF_XR);
    float* xs    = (float*)(ws + OFF_XS);
    float* score = (float*)(ws + OFF_SCORE);
    int*   pos   = (int*)(ws + OFF_POS);
    int*   keepn = (int*)(ws + OFF_KEEPN);
    float* keeps = (float*)(ws + OFF_KEEPS);
    int*   sums  = (int*)(ws + OFF_SUMS);
    float* xsum  = (float*)(ws + OFF_XSUM);
    float* cg    = (float*)(ws + OFF_CG);
    float* alpha = (float*)(ws + OFF_ALPHA);
    float* pvec  = (float*)(ws + OFF_PVEC);

    // ---- full-graph CSR (by dst) ----
    hipMemsetAsync(cnt, 0, NNODE * sizeof(int), stream);
    k_hist<<<EDGES / 256, 256, 0, stream>>>(edst_in, cnt, EDGES);
    k_scan_a<<<NNODE / 256, 256, 0, stream>>>(cnt, offA, sums, NNODE);
    k_scan_b<<<1, 256, 0, stream>>>(sums, NNODE / 256, offA, NNODE);
    k_scan_c<<<NNODE / 256, 256, 0, stream>>>(offA, sums, NNODE);
    hipMemsetAsync(cnt, 0, NNODE * sizeof(int), stream);
    k_fill<<<EDGES / 256, 256, 0, stream>>>(esrc_in, edst_in, offA, cnt, esrc, EDGES);
    k_segsort<<<NNODE / 256, 256, 0, stream>>>(offA, esrc, NNODE);
    k_dinv<<<NNODE / 256, 256, 0, stream>>>(offA, dinv, NNODE);

    // ---- 3 GCN layers into hcat column slices ----
    dim3 mmg(2, NNODE / 64);
    k_matmul<false><<<mmg, 256, 0, stream>>>(x, 128, nullptr, nullptr, W1, 128, 128, xw, 128);
    k_agg_lds<512, 64><<<256, 512, 0, stream>>>(xw, offA, esrc, dinv, b1, hcat + 0, DCAT);
    k_matmul<false><<<mmg, 256, 0, stream>>>(hcat, DCAT, nullptr, nullptr, W2, 128, 128, xw, 128);
    k_agg_lds<512, 64><<<256, 512, 0, stream>>>(xw, offA, esrc, dinv, b2, hcat + 128, DCAT);
    k_matmul<false><<<mmg, 256, 0, stream>>>(hcat + 128, DCAT, nullptr, nullptr, W3, 128, 128, xw, 128);
    k_agg_lds<512, 64><<<256, 512, 0, stream>>>(xw, offA, esrc, dinv, b3, hcat + 256, DCAT);

    // ---- SAGPool scoring + top-K ----
    k_xrxs<<<NNODE / 4, 256, 0, stream>>>(hcat, pWr, pWs, xr, xs);
    k_score<<<NNODE / 256, 256, 0, stream>>>(offA, esrc, xr, xs, pb, score);
    k_topk<<<256, 256, 0, stream>>>(score, keepn, keeps, pos);

    // ---- pooled CSR (filtered, remapped edges) ----
    hipMemsetAsync(cnt, 0, NPOOL * sizeof(int), stream);
    k_hist_p<<<EDGES / 256, 256, 0, stream>>>(esrc_in, edst_in, pos, cnt, EDGES);
    k_scan_a<<<NPOOL / 256, 256, 0, stream>>>(cnt, offA, sums, NPOOL);
    k_scan_b<<<1, 256, 0, stream>>>(sums, NPOOL / 256, offA, NPOOL);
    k_scan_c<<<NPOOL / 256, 256, 0, stream>>>(offA, sums, NPOOL);
    hipMemsetAsync(cnt, 0, NPOOL * sizeof(int), stream);
    k_fill_p<<<EDGES / 256, 256, 0, stream>>>(esrc_in, edst_in, pos, offA, cnt, esrc, EDGES);
    k_segsort<<<NPOOL / 256, 256, 0, stream>>>(offA, esrc, NPOOL);
    k_dinv<<<NPOOL / 256, 256, 0, stream>>>(offA, dinvp, NPOOL);

    // ---- pooled GCN conv (gather+scale A rows from hcat) ----
    dim3 mmp(2, NPOOL / 64);
    k_matmul<true><<<mmp, 256, 0, stream>>>(hcat, DCAT, keepn, keeps, fW, 128, DCAT, xwp, 128);
    k_agg_lds<128, 128><<<256, 512, 0, stream>>>(xwp, offA, esrc, dinvp, fb, hp, 128);

    // ---- attention pool + head ----
    k_xsum<<<NGG, 128, 0, stream>>>(hp, xsum);
    k_cg<<<NGG, 128, 0, stream>>>(xsum, gpW, cg);
    k_alpha<<<NPOOL / 4, 256, 0, stream>>>(hp, cg, alpha);
    k_wsum<<<NGG, 128, 0, stream>>>(hp, alpha, pvec);
    k_head<<<BG, 128, 0, stream>>>(pvec, l1W, l1b, l2W, l2b, l3W, l3b, out);
    k_batchout<<<256, 256, 0, stream>>>(out);
}